// Round 1
// baseline (2350.152 us; speedup 1.0000x reference)
//
#include <hip/hip_runtime.h>
#include <hip/hip_bf16.h>
#include <math.h>

#define IHW 224
#define DIN 16
#define DOUT 8
#define HO 112
#define PO 56

// ---------------- conv3d 7x7x7 stride2 SAME + ReLU ----------------
// in: [B][C][16][224][224], w: [64][C][7][7][7], out: [B][64][8][112][112]
// block: fixed (b, do, ho); 256 thr = 16 ocg x 16 wl; thread: 4 oc x 7 wo (wo = wl+16i)
template<int C>
__global__ __launch_bounds__(256) void conv_stem(
    const float* __restrict__ in, const float* __restrict__ w,
    float* __restrict__ out)
{
  const int ho  = blockIdx.x;   // 0..111
  const int dd  = blockIdx.y;   // 0..7
  const int b   = blockIdx.z;   // 0..1
  const int tid = threadIdx.x;
  const int wl  = tid & 15;
  const int ocg = tid >> 4;     // 0..15
  const int oc0 = ocg * 4;

  __shared__ float sIn[C][7][232];  // s = iw+2, s in [0,229); padded to 232

  float acc[4][7];
#pragma unroll
  for (int j = 0; j < 4; j++)
#pragma unroll
    for (int i = 0; i < 7; i++) acc[j][i] = 0.f;

  for (int kd = 0; kd < 7; kd++) {
    const int id = 2 * dd + kd - 2;
    if (id < 0 || id >= DIN) continue;  // block-uniform
    __syncthreads();
    const int total = C * 7 * 232;
    for (int idx = tid; idx < total; idx += 256) {
      const int s  = idx % 232;
      const int rc = idx / 232;
      const int kh = rc % 7;
      const int c  = rc / 7;
      const int ih = 2 * ho + kh - 2;
      const int iw = s - 2;
      float v = 0.f;
      if (s < 229 && ih >= 0 && ih < IHW && iw >= 0 && iw < IHW)
        v = in[(((size_t)(b * C + c) * DIN + id) * IHW + ih) * IHW + iw];
      sIn[c][kh][s] = v;
    }
    __syncthreads();

    for (int c = 0; c < C; c++) {
      for (int kh = 0; kh < 7; kh++) {
        float wv[4][7];
#pragma unroll
        for (int j = 0; j < 4; j++) {
          const float* wp = w + ((size_t)(oc0 + j) * C + c) * 343 + kd * 49 + kh * 7;
#pragma unroll
          for (int kw = 0; kw < 7; kw++) wv[j][kw] = wp[kw];
        }
#pragma unroll
        for (int i = 0; i < 7; i++) {
          const int sbase = 2 * (wl + 16 * i);
#pragma unroll
          for (int kw = 0; kw < 7; kw++) {
            const float a = sIn[c][kh][sbase + kw];
#pragma unroll
            for (int j = 0; j < 4; j++) acc[j][i] += a * wv[j][kw];
          }
        }
      }
    }
  }

#pragma unroll
  for (int j = 0; j < 4; j++) {
    const int oc = oc0 + j;
    const size_t base = (((size_t)(b * 64 + oc) * DOUT + dd) * HO + ho) * HO;
#pragma unroll
    for (int i = 0; i < 7; i++) {
      const int wo = wl + 16 * i;
      out[base + wo] = fmaxf(acc[j][i], 0.f);
    }
  }
}

// ---------------- maxpool 3x3 s2 SAME (pad hi only) ----------------
// in: [.][112][112] -> out: [.][56][56];  n = B*64*8*56*56
__global__ void maxpool_k(const float* __restrict__ in, float* __restrict__ out, int n) {
  const int idx = blockIdx.x * 256 + threadIdx.x;
  if (idx >= n) return;
  const int wo = idx % PO;
  const int ho = (idx / PO) % PO;
  const int rest = idx / (PO * PO);
  const float* p = in + (size_t)rest * (HO * HO);
  float m = -1e30f;
  for (int dh = 0; dh < 3; dh++) {
    const int ih = 2 * ho + dh;
    if (ih >= HO) break;
    for (int dw = 0; dw < 3; dw++) {
      const int iw = 2 * wo + dw;
      if (iw >= HO) break;
      m = fmaxf(m, p[ih * HO + iw]);
    }
  }
  out[idx] = m;
}

// ---------------- FCL layer 1: X(256x25088 gathered) @ W1(25088x1024) ----------------
// BM=64 BN=128 BK=32, K split into 8 chunks of 3136 (98 iters). partials out.
__global__ __launch_bounds__(256) void fcl1_gemm(
    const float* __restrict__ pr, const float* __restrict__ pf,
    const float* __restrict__ W1, float* __restrict__ part)
{
  const int bm = blockIdx.x;  // 0..3
  const int bn = blockIdx.y;  // 0..7
  const int kc = blockIdx.z;  // 0..7
  const int tid = threadIdx.x;

  __shared__ float Xs[32][68];
  __shared__ float Ws[32][132];

  float acc[4][8];
#pragma unroll
  for (int i = 0; i < 4; i++)
#pragma unroll
    for (int j = 0; j < 8; j++) acc[i][j] = 0.f;

  const int tm = tid & 15;   // m0 = tm*4
  const int tn = tid >> 4;   // n0 = tn*8

  // X-load decode (row = bm*64 + m_load)
  const int m_load = tid & 63;
  const int kx0 = tid >> 6;  // 0..3
  const int r = bm * 64 + m_load;
  const int b  = r >> 7;
  const int t  = (r >> 4) & 7;
  const int hb = (r >> 2) & 3;
  const int wb = r & 3;

  const int n4  = tid & 31;
  const int kw0 = tid >> 5;  // 0..7

  for (int it = 0; it < 98; it++) {
    const int kbase = kc * 3136 + it * 32;
    // load X tile (gathered, 8 elems/thread)
#pragma unroll
    for (int jj = 0; jj < 8; jj++) {
      const int kk = kx0 + jj * 4;
      const int f = kbase + kk;
      const float* src = (f < 12544) ? pr : pf;
      const int fl = (f < 12544) ? f : f - 12544;
      const int c = fl / 196;
      const int rem = fl % 196;
      const int hi = rem / 14;
      const int wi = rem % 14;
      Xs[kk][m_load] =
          src[(((size_t)(b * 64 + c) * 8 + t) * PO + hb * 14 + hi) * PO + wb * 14 + wi];
    }
    // load W tile (16 elems/thread as float4)
#pragma unroll
    for (int p = 0; p < 4; p++) {
      const int kk = kw0 + p * 8;
      const float4 v = *reinterpret_cast<const float4*>(
          &W1[(size_t)(kbase + kk) * 1024 + bn * 128 + n4 * 4]);
      *reinterpret_cast<float4*>(&Ws[kk][n4 * 4]) = v;
    }
    __syncthreads();
#pragma unroll
    for (int kk = 0; kk < 32; kk++) {
      const float4 xa = *reinterpret_cast<const float4*>(&Xs[kk][tm * 4]);
      const float4 wa = *reinterpret_cast<const float4*>(&Ws[kk][tn * 8]);
      const float4 wb4 = *reinterpret_cast<const float4*>(&Ws[kk][tn * 8 + 4]);
      const float xs[4] = {xa.x, xa.y, xa.z, xa.w};
      const float ws8[8] = {wa.x, wa.y, wa.z, wa.w, wb4.x, wb4.y, wb4.z, wb4.w};
#pragma unroll
      for (int i = 0; i < 4; i++)
#pragma unroll
        for (int j = 0; j < 8; j++) acc[i][j] += xs[i] * ws8[j];
    }
    __syncthreads();
  }

#pragma unroll
  for (int i = 0; i < 4; i++) {
    const int row = bm * 64 + tm * 4 + i;
#pragma unroll
    for (int j = 0; j < 8; j++) {
      const int col = bn * 128 + tn * 8 + j;
      part[((size_t)kc * 256 + row) * 1024 + col] = acc[i][j];
    }
  }
}

__global__ void h1_reduce(const float* __restrict__ part, const float* __restrict__ b1,
                          float* __restrict__ h1) {
  const int idx = blockIdx.x * 256 + threadIdx.x;  // < 262144
  if (idx >= 262144) return;
  const int n = idx & 1023;
  float s = b1[n];
  for (int kc = 0; kc < 8; kc++) s += part[(size_t)kc * 262144 + idx];
  h1[idx] = fmaxf(s, 0.f);
}

// h2 = relu(h1 @ W2 + b2): one block per row
__global__ __launch_bounds__(256) void fcl2_k(const float* __restrict__ h1,
                                              const float* __restrict__ W2,
                                              const float* __restrict__ b2,
                                              float* __restrict__ h2) {
  const int r = blockIdx.x;
  const int n = threadIdx.x;
  __shared__ float xr[1024];
  for (int i = threadIdx.x; i < 1024; i += 256) xr[i] = h1[r * 1024 + i];
  __syncthreads();
  float s = b2[n];
  for (int k = 0; k < 1024; k++) s += xr[k] * W2[k * 256 + n];
  h2[r * 256 + n] = fmaxf(s, 0.f);
}

// mask_small[r] = sigmoid(h2[r] . W3 + b3)
__global__ void fcl3_k(const float* __restrict__ h2, const float* __restrict__ W3,
                       const float* __restrict__ b3, float* __restrict__ ms) {
  __shared__ float w[256];
  w[threadIdx.x] = W3[threadIdx.x];
  __syncthreads();
  const int r = threadIdx.x;
  float s = b3[0];
  for (int k = 0; k < 256; k++) s += h2[r * 256 + k] * w[k];
  ms[r] = 1.f / (1.f + expf(-s));
}

// trilinear upsample (half-pixel, edge clamp): (2,8,4,4) -> (2,16,224,224)
__global__ void upsample_k(const float* __restrict__ ms, float* __restrict__ mask) {
  const int idx = blockIdx.x * 256 + threadIdx.x;
  if (idx >= 2 * 16 * IHW * IHW) return;
  const int w = idx % IHW;
  const int h = (idx / IHW) % IHW;
  const int t = (idx / (IHW * IHW)) % 16;
  const int b = idx / (16 * IHW * IHW);

  const float tf = t * 0.5f - 0.25f;
  const float hf = (h + 0.5f) * (1.f / 56.f) - 0.5f;
  const float wf = (w + 0.5f) * (1.f / 56.f) - 0.5f;

  int t0 = (int)floorf(tf); const float ft = tf - t0;
  int h0 = (int)floorf(hf); const float fh = hf - h0;
  int w0 = (int)floorf(wf); const float fw = wf - w0;
  const int t1 = min(t0 + 1, 7); t0 = max(t0, 0);
  const int h1 = min(h0 + 1, 3); h0 = max(h0, 0);
  const int w1 = min(w0 + 1, 3); w0 = max(w0, 0);

  const float* p = ms + b * 128;  // [8][4][4]
  auto at = [&](int tt, int hh, int ww) { return p[(tt * 4 + hh) * 4 + ww]; };
  const float c00 = at(t0, h0, w0) * (1.f - fw) + at(t0, h0, w1) * fw;
  const float c01 = at(t0, h1, w0) * (1.f - fw) + at(t0, h1, w1) * fw;
  const float c10 = at(t1, h0, w0) * (1.f - fw) + at(t1, h0, w1) * fw;
  const float c11 = at(t1, h1, w0) * (1.f - fw) + at(t1, h1, w1) * fw;
  const float c0 = c00 * (1.f - fh) + c01 * fh;
  const float c1 = c10 * (1.f - fh) + c11 * fh;
  mask[idx] = c0 * (1.f - ft) + c1 * ft;
}

// masked = rgbs*m + bg*(1-m); flip -> m := 1-m
__global__ void masking_k(const float* __restrict__ rgbs, const float* __restrict__ mask,
                          const float* __restrict__ bg, float* __restrict__ out, int flip) {
  const int idx = blockIdx.x * 256 + threadIdx.x;
  if (idx >= 2 * 3 * 16 * IHW * IHW) return;
  const int hw = idx % (IHW * IHW);
  const int t = (idx / (IHW * IHW)) % 16;
  const int c = (idx / (16 * IHW * IHW)) % 3;
  const int b = idx / (3 * 16 * IHW * IHW);
  float m = mask[((size_t)(b * 16 + t)) * (IHW * IHW) + hw];
  if (flip) m = 1.f - m;
  out[idx] = rgbs[idx] * m + bg[c * (IHW * IHW) + hw] * (1.f - m);
}

// fused maxpool + spatial sum for feature head: one block per (b,oc,t)
__global__ __launch_bounds__(256) void pool_sum_k(const float* __restrict__ in,
                                                  float* __restrict__ psums) {
  const int blk = blockIdx.x;  // (b*64+oc)*8 + t, 1024 total
  const float* p = in + (size_t)blk * (HO * HO);
  float s = 0.f;
  for (int idx = threadIdx.x; idx < PO * PO; idx += 256) {
    const int ho = idx / PO, wo = idx % PO;
    float m = -1e30f;
    for (int dh = 0; dh < 3; dh++) {
      const int ih = 2 * ho + dh;
      if (ih >= HO) break;
      for (int dw = 0; dw < 3; dw++) {
        const int iw = 2 * wo + dw;
        if (iw >= HO) break;
        m = fmaxf(m, p[ih * HO + iw]);
      }
    }
    s += m;
  }
  __shared__ float red[256];
  red[threadIdx.x] = s;
  __syncthreads();
  for (int off = 128; off > 0; off >>= 1) {
    if (threadIdx.x < off) red[threadIdx.x] += red[threadIdx.x + off];
    __syncthreads();
  }
  if (threadIdx.x == 0) psums[blk] = red[0];
}

// out[b][l] = bl[l] + sum_oc (sum_t psums[b][oc][t] / 25088) * Wl[oc][l]
__global__ void logits_k(const float* __restrict__ psums, const float* __restrict__ Wl,
                         const float* __restrict__ bl, float* __restrict__ out) {
  const int idx = blockIdx.x * 256 + threadIdx.x;
  if (idx >= 800) return;
  const int b = idx / 400, l = idx % 400;
  float s = bl[l];
  for (int oc = 0; oc < 64; oc++) {
    float ps = 0.f;
    for (int t = 0; t < 8; t++) ps += psums[(b * 64 + oc) * 8 + t];
    s += (ps * (1.f / 25088.f)) * Wl[oc * 400 + l];
  }
  out[b * 400 + l] = s;
}

extern "C" void kernel_launch(void* const* d_in, const int* in_sizes, int n_in,
                              void* d_out, int out_size, void* d_ws, size_t ws_size,
                              hipStream_t stream) {
  const float* rgbs   = (const float*)d_in[0];
  const float* flows  = (const float*)d_in[1];
  const float* bg     = (const float*)d_in[2];
  const float* w_rgb  = (const float*)d_in[3];
  const float* w_flow = (const float*)d_in[4];
  const float* w_feat = (const float*)d_in[5];
  const float* W1     = (const float*)d_in[6];
  const float* b1     = (const float*)d_in[7];
  const float* W2     = (const float*)d_in[8];
  const float* b2     = (const float*)d_in[9];
  const float* W3     = (const float*)d_in[10];
  const float* b3     = (const float*)d_in[11];
  const float* Wl     = (const float*)d_in[12];
  const float* bl     = (const float*)d_in[13];
  float* out = (float*)d_out;

  float* ws = (float*)d_ws;
  float* convbuf     = ws;                       // 12,845,056
  float* pooled_rgb  = ws + 12845056;            // 3,211,264
  float* pooled_flow = ws + 16056320;            // 3,211,264
  float* masked      = ws + 12845056;            // 4,816,896 (reuses pooled area later)
  float* h1part      = ws + 19267584;            // 2,097,152
  float* h1          = ws + 21364736;            // 262,144
  float* h2          = ws + 21626880;            // 65,536
  float* msmall      = ws + 21692416;            // 256
  float* psums0      = ws + 21692672;            // 1024
  float* psums1      = ws + 21693696;            // 1024

  float* mask_full = out + 1600;  // (2,16,224,224)

  const dim3 cgrid(112, 8, 2);

  // --- mask branch ---
  conv_stem<3><<<cgrid, 256, 0, stream>>>(rgbs, w_rgb, convbuf);
  maxpool_k<<<(3211264 + 255) / 256, 256, 0, stream>>>(convbuf, pooled_rgb, 3211264);
  conv_stem<2><<<cgrid, 256, 0, stream>>>(flows, w_flow, convbuf);
  maxpool_k<<<(3211264 + 255) / 256, 256, 0, stream>>>(convbuf, pooled_flow, 3211264);

  fcl1_gemm<<<dim3(4, 8, 8), 256, 0, stream>>>(pooled_rgb, pooled_flow, W1, h1part);
  h1_reduce<<<1024, 256, 0, stream>>>(h1part, b1, h1);
  fcl2_k<<<256, 256, 0, stream>>>(h1, W2, b2, h2);
  fcl3_k<<<1, 256, 0, stream>>>(h2, W3, b3, msmall);
  upsample_k<<<(1605632 + 255) / 256, 256, 0, stream>>>(msmall, mask_full);

  // --- feature head 0 ---
  masking_k<<<(4816896 + 255) / 256, 256, 0, stream>>>(rgbs, mask_full, bg, masked, 0);
  conv_stem<3><<<cgrid, 256, 0, stream>>>(masked, w_feat, convbuf);
  pool_sum_k<<<1024, 256, 0, stream>>>(convbuf, psums0);

  // --- feature head 1 ---
  masking_k<<<(4816896 + 255) / 256, 256, 0, stream>>>(rgbs, mask_full, bg, masked, 1);
  conv_stem<3><<<cgrid, 256, 0, stream>>>(masked, w_feat, convbuf);
  pool_sum_k<<<1024, 256, 0, stream>>>(convbuf, psums1);

  logits_k<<<4, 256, 0, stream>>>(psums0, Wl, bl, out);
  logits_k<<<4, 256, 0, stream>>>(psums1, Wl, bl, out + 800);
}

// Round 2
// 1050.238 us; speedup vs baseline: 2.2377x; 2.2377x over previous
//
#include <hip/hip_runtime.h>
#include <hip/hip_bf16.h>
#include <math.h>

#define IHW 224
#define DIN 16
#define DOUT 8
#define HO 112
#define PO 56

typedef __bf16 bf16x8 __attribute__((ext_vector_type(8)));
typedef float f32x4 __attribute__((ext_vector_type(4)));

__device__ __forceinline__ ushort f2bf(float f) {
  uint u = __float_as_uint(f);
  uint r = (u + 0x7FFFu + ((u >> 16) & 1u)) >> 16;
  return (ushort)r;
}

// ---------------- weight prep: f32 [64][C][7][7][7] -> bf16 [oc][kw][KPAD] ----------------
// k = kd*(C*7) + c*7 + kh  (zeros for k >= C*49)
template<int C>
__global__ __launch_bounds__(256) void wprep(const float* __restrict__ w, ushort* __restrict__ wB) {
  constexpr int C7 = C * 7, KREAL = C * 49, KPAD = (C == 3) ? 160 : 128;
  const int idx = blockIdx.x * 256 + threadIdx.x;
  if (idx >= 64 * 7 * KPAD) return;
  const int k = idx % KPAD;
  const int rest = idx / KPAD;
  const int kw = rest % 7;
  const int oc = rest / 7;
  float val = 0.f;
  if (k < KREAL) {
    const int kd = k / C7, rem = k % C7, c = rem / 7, kh = rem % 7;
    val = w[(((oc * C + c) * 7 + kd) * 7 + kh) * 7 + kw];
  }
  wB[idx] = f2bf(val);
}

// ---------------- conv3d 7x7x7 s2 SAME + ReLU via bf16 MFMA ----------------
// block = (ho, dd, b); computes out[b][0..63][dd][ho][0..111]
// LDS: sT[s=0..228][KPAD] bf16, XOR-swizzled; A-frag = ds_read_b128 at s=2wo+kw
template<int C>
__global__ __launch_bounds__(256) void conv_mfma(
    const float* __restrict__ in, const ushort* __restrict__ wB,
    float* __restrict__ out)
{
  constexpr int C7 = C * 7, KREAL = C * 49;
  constexpr int KPAD = (C == 3) ? 160 : 128;
  constexpr int NKIT = KPAD / 32;
  constexpr int ROWB = KPAD * 2;       // bytes per s-row
  constexpr int KG = KPAD / 4;         // k-groups of 4
  constexpr int UNITS = KG * 4;        // (kgroup, schunk) work units

  __shared__ char smem[229 * ROWB];

  const int ho = blockIdx.x;
  const int dd = blockIdx.y;
  const int b  = blockIdx.z;
  const int tid = threadIdx.x;
  const int lane = tid & 63;
  const int wv = tid >> 6;            // wave 0..3

  // ---- stage input slice, transposed + bf16 + swizzled ----
  for (int u = wv; u < UNITS; u += 4) {
    const int kg = u >> 2, sc = u & 2 ? (u & 3) : (u & 3);  // sc = u&3
    const int s = (u & 3) * 64 + lane;
    if (s < 229) {
      const int iw = s - 2;
      ushort pk[4];
#pragma unroll
      for (int j = 0; j < 4; j++) {
        const int k = kg * 4 + j;
        float val = 0.f;
        if (k < KREAL) {
          const int kd = k / C7, rem = k % C7, c = rem / 7, kh = rem % 7;
          const int id = 2 * dd + kd - 2;
          const int ih = 2 * ho + kh - 2;
          if (iw >= 0 && iw < IHW && id >= 0 && id < DIN && ih >= 0 && ih < IHW)
            val = in[(((size_t)(b * C + c) * DIN + id) * IHW + ih) * IHW + iw];
        }
        pk[j] = f2bf(val);
      }
      int byte = s * ROWB + kg * 8;
      byte ^= ((s >> 1) & 7) << 4;
      *reinterpret_cast<ushort4*>(smem + byte) =
          make_ushort4(pk[0], pk[1], pk[2], pk[3]);
    }
  }
  __syncthreads();

  // ---- MFMA compute: wave = (mhalf, nhalf); 4 M-tiles x 2 N-tiles ----
  const int mhalf = wv >> 1, nhalf = wv & 1;
  const int row = lane & 15, ksub = lane >> 4;

  int s0[4];
#pragma unroll
  for (int mt = 0; mt < 4; mt++) {
    const int wo = mhalf * 64 + mt * 16 + row;
    int ss = 2 * wo;
    if (mhalf == 1 && mt == 3) ss -= 32;  // dead tile (wo 112..127): clamp
    s0[mt] = ss;
  }
  const ushort* wq0 = wB + (size_t)(nhalf * 32 + row) * (7 * KPAD) + ksub * 8;
  const ushort* wq1 = wq0 + (size_t)16 * (7 * KPAD);

  f32x4 acc[4][2] = {};

#pragma unroll
  for (int kw = 0; kw < 7; kw++) {
#pragma unroll
    for (int kit = 0; kit < NKIT; kit++) {
      const bf16x8 b0 = *reinterpret_cast<const bf16x8*>(wq0 + kw * KPAD + kit * 32);
      const bf16x8 b1 = *reinterpret_cast<const bf16x8*>(wq1 + kw * KPAD + kit * 32);
#pragma unroll
      for (int mt = 0; mt < 4; mt++) {
        const int s = s0[mt] + kw;
        const int byte = (s * ROWB + (kit * 4 + ksub) * 16) ^ (((s >> 1) & 7) << 4);
        const bf16x8 a = *reinterpret_cast<const bf16x8*>(smem + byte);
        acc[mt][0] = __builtin_amdgcn_mfma_f32_16x16x32_bf16(a, b0, acc[mt][0], 0, 0, 0);
        acc[mt][1] = __builtin_amdgcn_mfma_f32_16x16x32_bf16(a, b1, acc[mt][1], 0, 0, 0);
      }
    }
  }

  // ---- epilogue: transpose via LDS, coalesced store ----
  __syncthreads();
  float* eLDS = reinterpret_cast<float*>(smem);  // [64][116]
#pragma unroll
  for (int mt = 0; mt < 4; mt++) {
    const int wo_b = mhalf * 64 + mt * 16 + ksub * 4;
    if (wo_b < 112) {
#pragma unroll
      for (int n = 0; n < 2; n++) {
        const int oc = nhalf * 32 + n * 16 + row;
        f32x4 r4;
#pragma unroll
        for (int r = 0; r < 4; r++) r4[r] = fmaxf(acc[mt][n][r], 0.f);
        *reinterpret_cast<f32x4*>(eLDS + oc * 116 + wo_b) = r4;
      }
    }
  }
  __syncthreads();
  for (int i = 0; i < 28; i++) {
    const int idx = i * 256 + tid;        // 0..7167
    const int oc = idx / 112;
    const int wo = idx - oc * 112;
    out[((size_t)(b * 64 + oc) * DOUT + dd) * (HO * HO) + ho * HO + wo] =
        eLDS[oc * 116 + wo];
  }
}

// ---------------- maxpool 3x3 s2 SAME (pad hi only) ----------------
__global__ void maxpool_k(const float* __restrict__ in, float* __restrict__ out, int n) {
  const int idx = blockIdx.x * 256 + threadIdx.x;
  if (idx >= n) return;
  const int wo = idx % PO;
  const int ho = (idx / PO) % PO;
  const int rest = idx / (PO * PO);
  const float* p = in + (size_t)rest * (HO * HO);
  float m = -1e30f;
  for (int dh = 0; dh < 3; dh++) {
    const int ih = 2 * ho + dh;
    if (ih >= HO) break;
    for (int dw = 0; dw < 3; dw++) {
      const int iw = 2 * wo + dw;
      if (iw >= HO) break;
      m = fmaxf(m, p[ih * HO + iw]);
    }
  }
  out[idx] = m;
}

// ---------------- FCL layer 1 ----------------
__global__ __launch_bounds__(256) void fcl1_gemm(
    const float* __restrict__ pr, const float* __restrict__ pf,
    const float* __restrict__ W1, float* __restrict__ part)
{
  const int bm = blockIdx.x;
  const int bn = blockIdx.y;
  const int kc = blockIdx.z;
  const int tid = threadIdx.x;

  __shared__ float Xs[32][68];
  __shared__ float Ws[32][132];

  float acc[4][8];
#pragma unroll
  for (int i = 0; i < 4; i++)
#pragma unroll
    for (int j = 0; j < 8; j++) acc[i][j] = 0.f;

  const int tm = tid & 15;
  const int tn = tid >> 4;

  const int m_load = tid & 63;
  const int kx0 = tid >> 6;
  const int r = bm * 64 + m_load;
  const int b  = r >> 7;
  const int t  = (r >> 4) & 7;
  const int hb = (r >> 2) & 3;
  const int wb = r & 3;

  const int n4  = tid & 31;
  const int kw0 = tid >> 5;

  for (int it = 0; it < 98; it++) {
    const int kbase = kc * 3136 + it * 32;
#pragma unroll
    for (int jj = 0; jj < 8; jj++) {
      const int kk = kx0 + jj * 4;
      const int f = kbase + kk;
      const float* src = (f < 12544) ? pr : pf;
      const int fl = (f < 12544) ? f : f - 12544;
      const int c = fl / 196;
      const int rem = fl % 196;
      const int hi = rem / 14;
      const int wi = rem % 14;
      Xs[kk][m_load] =
          src[(((size_t)(b * 64 + c) * 8 + t) * PO + hb * 14 + hi) * PO + wb * 14 + wi];
    }
#pragma unroll
    for (int p = 0; p < 4; p++) {
      const int kk = kw0 + p * 8;
      const float4 v = *reinterpret_cast<const float4*>(
          &W1[(size_t)(kbase + kk) * 1024 + bn * 128 + n4 * 4]);
      *reinterpret_cast<float4*>(&Ws[kk][n4 * 4]) = v;
    }
    __syncthreads();
#pragma unroll
    for (int kk = 0; kk < 32; kk++) {
      const float4 xa = *reinterpret_cast<const float4*>(&Xs[kk][tm * 4]);
      const float4 wa = *reinterpret_cast<const float4*>(&Ws[kk][tn * 8]);
      const float4 wb4 = *reinterpret_cast<const float4*>(&Ws[kk][tn * 8 + 4]);
      const float xs[4] = {xa.x, xa.y, xa.z, xa.w};
      const float ws8[8] = {wa.x, wa.y, wa.z, wa.w, wb4.x, wb4.y, wb4.z, wb4.w};
#pragma unroll
      for (int i = 0; i < 4; i++)
#pragma unroll
        for (int j = 0; j < 8; j++) acc[i][j] += xs[i] * ws8[j];
    }
    __syncthreads();
  }

#pragma unroll
  for (int i = 0; i < 4; i++) {
    const int rr = bm * 64 + tm * 4 + i;
#pragma unroll
    for (int j = 0; j < 8; j++) {
      const int col = bn * 128 + tn * 8 + j;
      part[((size_t)kc * 256 + rr) * 1024 + col] = acc[i][j];
    }
  }
}

__global__ void h1_reduce(const float* __restrict__ part, const float* __restrict__ b1,
                          float* __restrict__ h1) {
  const int idx = blockIdx.x * 256 + threadIdx.x;
  if (idx >= 262144) return;
  const int n = idx & 1023;
  float s = b1[n];
  for (int kc = 0; kc < 8; kc++) s += part[(size_t)kc * 262144 + idx];
  h1[idx] = fmaxf(s, 0.f);
}

__global__ __launch_bounds__(256) void fcl2_k(const float* __restrict__ h1,
                                              const float* __restrict__ W2,
                                              const float* __restrict__ b2,
                                              float* __restrict__ h2) {
  const int r = blockIdx.x;
  const int n = threadIdx.x;
  __shared__ float xr[1024];
  for (int i = threadIdx.x; i < 1024; i += 256) xr[i] = h1[r * 1024 + i];
  __syncthreads();
  float s = b2[n];
  for (int k = 0; k < 1024; k++) s += xr[k] * W2[k * 256 + n];
  h2[r * 256 + n] = fmaxf(s, 0.f);
}

__global__ void fcl3_k(const float* __restrict__ h2, const float* __restrict__ W3,
                       const float* __restrict__ b3, float* __restrict__ ms) {
  __shared__ float w[256];
  w[threadIdx.x] = W3[threadIdx.x];
  __syncthreads();
  const int r = threadIdx.x;
  float s = b3[0];
  for (int k = 0; k < 256; k++) s += h2[r * 256 + k] * w[k];
  ms[r] = 1.f / (1.f + expf(-s));
}

__global__ void upsample_k(const float* __restrict__ ms, float* __restrict__ mask) {
  const int idx = blockIdx.x * 256 + threadIdx.x;
  if (idx >= 2 * 16 * IHW * IHW) return;
  const int w = idx % IHW;
  const int h = (idx / IHW) % IHW;
  const int t = (idx / (IHW * IHW)) % 16;
  const int b = idx / (16 * IHW * IHW);

  const float tf = t * 0.5f - 0.25f;
  const float hf = (h + 0.5f) * (1.f / 56.f) - 0.5f;
  const float wf = (w + 0.5f) * (1.f / 56.f) - 0.5f;

  int t0 = (int)floorf(tf); const float ft = tf - t0;
  int h0 = (int)floorf(hf); const float fh = hf - h0;
  int w0 = (int)floorf(wf); const float fw = wf - w0;
  const int t1 = min(t0 + 1, 7); t0 = max(t0, 0);
  const int h1 = min(h0 + 1, 3); h0 = max(h0, 0);
  const int w1 = min(w0 + 1, 3); w0 = max(w0, 0);

  const float* p = ms + b * 128;
  auto at = [&](int tt, int hh, int ww) { return p[(tt * 4 + hh) * 4 + ww]; };
  const float c00 = at(t0, h0, w0) * (1.f - fw) + at(t0, h0, w1) * fw;
  const float c01 = at(t0, h1, w0) * (1.f - fw) + at(t0, h1, w1) * fw;
  const float c10 = at(t1, h0, w0) * (1.f - fw) + at(t1, h0, w1) * fw;
  const float c11 = at(t1, h1, w0) * (1.f - fw) + at(t1, h1, w1) * fw;
  const float c0 = c00 * (1.f - fh) + c01 * fh;
  const float c1 = c10 * (1.f - fh) + c11 * fh;
  mask[idx] = c0 * (1.f - ft) + c1 * ft;
}

__global__ void masking_k(const float* __restrict__ rgbs, const float* __restrict__ mask,
                          const float* __restrict__ bg, float* __restrict__ out, int flip) {
  const int idx = blockIdx.x * 256 + threadIdx.x;
  if (idx >= 2 * 3 * 16 * IHW * IHW) return;
  const int hw = idx % (IHW * IHW);
  const int t = (idx / (IHW * IHW)) % 16;
  const int c = (idx / (16 * IHW * IHW)) % 3;
  const int b = idx / (3 * 16 * IHW * IHW);
  float m = mask[((size_t)(b * 16 + t)) * (IHW * IHW) + hw];
  if (flip) m = 1.f - m;
  out[idx] = rgbs[idx] * m + bg[c * (IHW * IHW) + hw] * (1.f - m);
}

__global__ __launch_bounds__(256) void pool_sum_k(const float* __restrict__ in,
                                                  float* __restrict__ psums) {
  const int blk = blockIdx.x;
  const float* p = in + (size_t)blk * (HO * HO);
  float s = 0.f;
  for (int idx = threadIdx.x; idx < PO * PO; idx += 256) {
    const int ho = idx / PO, wo = idx % PO;
    float m = -1e30f;
    for (int dh = 0; dh < 3; dh++) {
      const int ih = 2 * ho + dh;
      if (ih >= HO) break;
      for (int dw = 0; dw < 3; dw++) {
        const int iw = 2 * wo + dw;
        if (iw >= HO) break;
        m = fmaxf(m, p[ih * HO + iw]);
      }
    }
    s += m;
  }
  __shared__ float red[256];
  red[threadIdx.x] = s;
  __syncthreads();
  for (int off = 128; off > 0; off >>= 1) {
    if (threadIdx.x < off) red[threadIdx.x] += red[threadIdx.x + off];
    __syncthreads();
  }
  if (threadIdx.x == 0) psums[blk] = red[0];
}

__global__ void logits_k(const float* __restrict__ psums, const float* __restrict__ Wl,
                         const float* __restrict__ bl, float* __restrict__ out) {
  const int idx = blockIdx.x * 256 + threadIdx.x;
  if (idx >= 800) return;
  const int b = idx / 400, l = idx % 400;
  float s = bl[l];
  for (int oc = 0; oc < 64; oc++) {
    float ps = 0.f;
    for (int t = 0; t < 8; t++) ps += psums[(b * 64 + oc) * 8 + t];
    s += (ps * (1.f / 25088.f)) * Wl[oc * 400 + l];
  }
  out[b * 400 + l] = s;
}

extern "C" void kernel_launch(void* const* d_in, const int* in_sizes, int n_in,
                              void* d_out, int out_size, void* d_ws, size_t ws_size,
                              hipStream_t stream) {
  const float* rgbs   = (const float*)d_in[0];
  const float* flows  = (const float*)d_in[1];
  const float* bg     = (const float*)d_in[2];
  const float* w_rgb  = (const float*)d_in[3];
  const float* w_flow = (const float*)d_in[4];
  const float* w_feat = (const float*)d_in[5];
  const float* W1     = (const float*)d_in[6];
  const float* b1     = (const float*)d_in[7];
  const float* W2     = (const float*)d_in[8];
  const float* b2     = (const float*)d_in[9];
  const float* W3     = (const float*)d_in[10];
  const float* b3     = (const float*)d_in[11];
  const float* Wl     = (const float*)d_in[12];
  const float* bl     = (const float*)d_in[13];
  float* out = (float*)d_out;

  float* ws = (float*)d_ws;
  float* convbuf     = ws;                       // 12,845,056
  float* pooled_rgb  = ws + 12845056;            // 3,211,264
  float* pooled_flow = ws + 16056320;            // 3,211,264
  float* masked      = ws + 12845056;            // 4,816,896 (reuses pooled area later)
  float* h1part      = ws + 19267584;            // 2,097,152
  float* h1          = ws + 21364736;            // 262,144
  float* h2          = ws + 21626880;            // 65,536
  float* msmall      = ws + 21692416;            // 256
  float* psums0      = ws + 21692672;            // 1024
  float* psums1      = ws + 21693696;            // 1024

  // bf16 packed weights live inside the h1part region (dead until fcl1 /
  // dead again after h1_reduce)
  ushort* wrgb_b  = (ushort*)(ws + 19267584);          // 71,680 ush
  ushort* wflow_b = wrgb_b + 71680;                    // 57,344 ush
  ushort* wfeat_b = (ushort*)(ws + 19267584);          // re-prepped later

  float* mask_full = out + 1600;

  const dim3 cgrid(112, 8, 2);

  // --- weight prep (mask branch) ---
  wprep<3><<<(64 * 7 * 160 + 255) / 256, 256, 0, stream>>>(w_rgb, wrgb_b);
  wprep<2><<<(64 * 7 * 128 + 255) / 256, 256, 0, stream>>>(w_flow, wflow_b);

  // --- mask branch stems ---
  conv_mfma<3><<<cgrid, 256, 0, stream>>>(rgbs, wrgb_b, convbuf);
  maxpool_k<<<(3211264 + 255) / 256, 256, 0, stream>>>(convbuf, pooled_rgb, 3211264);
  conv_mfma<2><<<cgrid, 256, 0, stream>>>(flows, wflow_b, convbuf);
  maxpool_k<<<(3211264 + 255) / 256, 256, 0, stream>>>(convbuf, pooled_flow, 3211264);

  fcl1_gemm<<<dim3(4, 8, 8), 256, 0, stream>>>(pooled_rgb, pooled_flow, W1, h1part);
  h1_reduce<<<1024, 256, 0, stream>>>(h1part, b1, h1);

  // h1part now dead -> prep feature weights into the same region
  wprep<3><<<(64 * 7 * 160 + 255) / 256, 256, 0, stream>>>(w_feat, wfeat_b);

  fcl2_k<<<256, 256, 0, stream>>>(h1, W2, b2, h2);
  fcl3_k<<<1, 256, 0, stream>>>(h2, W3, b3, msmall);
  upsample_k<<<(1605632 + 255) / 256, 256, 0, stream>>>(msmall, mask_full);

  // --- feature head 0 ---
  masking_k<<<(4816896 + 255) / 256, 256, 0, stream>>>(rgbs, mask_full, bg, masked, 0);
  conv_mfma<3><<<cgrid, 256, 0, stream>>>(masked, wfeat_b, convbuf);
  pool_sum_k<<<1024, 256, 0, stream>>>(convbuf, psums0);

  // --- feature head 1 ---
  masking_k<<<(4816896 + 255) / 256, 256, 0, stream>>>(rgbs, mask_full, bg, masked, 1);
  conv_mfma<3><<<cgrid, 256, 0, stream>>>(masked, wfeat_b, convbuf);
  pool_sum_k<<<1024, 256, 0, stream>>>(convbuf, psums1);

  logits_k<<<4, 256, 0, stream>>>(psums0, Wl, bl, out);
  logits_k<<<4, 256, 0, stream>>>(psums1, Wl, bl, out + 800);
}

// Round 4
// 660.548 us; speedup vs baseline: 3.5579x; 1.5899x over previous
//
#include <hip/hip_runtime.h>
#include <hip/hip_bf16.h>
#include <math.h>

#define IHW 224
#define DIN 16
#define DOUT 8
#define HO 112
#define PO 56

typedef __bf16 bf16x8 __attribute__((ext_vector_type(8)));
typedef float f32x4 __attribute__((ext_vector_type(4)));
typedef float f32x16 __attribute__((ext_vector_type(16)));

__device__ __forceinline__ ushort f2bf(float f) {
  uint u = __float_as_uint(f);
  uint r = (u + 0x7FFFu + ((u >> 16) & 1u)) >> 16;
  return (ushort)r;
}

// ---------------- weight prep: f32 [64][C][7][7][7] -> bf16 [oc][kw][KPAD] ----------------
template<int C>
__global__ __launch_bounds__(256) void wprep(const float* __restrict__ w, ushort* __restrict__ wB) {
  constexpr int C7 = C * 7, KREAL = C * 49, KPAD = (C == 3) ? 160 : 128;
  const int idx = blockIdx.x * 256 + threadIdx.x;
  if (idx >= 64 * 7 * KPAD) return;
  const int k = idx % KPAD;
  const int rest = idx / KPAD;
  const int kw = rest % 7;
  const int oc = rest / 7;
  float val = 0.f;
  if (k < KREAL) {
    const int kd = k / C7, rem = k % C7, c = rem / 7, kh = rem % 7;
    val = w[(((oc * C + c) * 7 + kd) * 7 + kh) * 7 + kw];
  }
  wB[idx] = f2bf(val);
}

// ---------------- conv3d 7x7x7 s2 SAME + ReLU via bf16 MFMA ----------------
// block = (ho, dd, b); out[b][0..63][dd][ho][0..111]
template<int C>
__global__ __launch_bounds__(256) void conv_mfma(
    const float* __restrict__ in, const ushort* __restrict__ wB,
    float* __restrict__ out)
{
  constexpr int C7 = C * 7, KREAL = C * 49;
  constexpr int KPAD = (C == 3) ? 160 : 128;
  constexpr int NKIT = KPAD / 32;
  constexpr int ROWB = KPAD * 2;
  constexpr int KG = KPAD / 4;

  __shared__ char smem[229 * ROWB];
  __shared__ int offt[KPAD];

  const int ho = blockIdx.x;
  const int dd = blockIdx.y;
  const int b  = blockIdx.z;
  const int tid = threadIdx.x;
  const int lane = tid & 63;
  const int wv = tid >> 6;

  // ---- per-block k -> plane-offset table ----
  for (int k = tid; k < KPAD; k += 256) {
    int off = -1;
    if (k < KREAL) {
      const int kd = k / C7, rem = k % C7, c = rem / 7, kh = rem % 7;
      const int id = 2 * dd + kd - 2;
      const int ih = 2 * ho + kh - 2;
      if (id >= 0 && id < DIN && ih >= 0 && ih < IHW)
        off = (((b * C + c) * DIN + id) * IHW + ih) * IHW;
    }
    offt[k] = off;
  }
  __syncthreads();

  // ---- stage input slice: transposed sT[s][k] bf16, XOR-swizzled ----
  if (tid < 229) {
    const int iw = tid - 2;
    const bool wok = (iw >= 0) && (iw < IHW);
    for (int kg = 0; kg < KG; kg++) {
      const int4 ot = *reinterpret_cast<const int4*>(&offt[kg * 4]);
      const int offs[4] = {ot.x, ot.y, ot.z, ot.w};
      ushort pk[4];
#pragma unroll
      for (int j = 0; j < 4; j++) {
        float v = 0.f;
        if (wok && offs[j] >= 0) v = in[offs[j] + iw];
        pk[j] = f2bf(v);
      }
      int byte = tid * ROWB + kg * 8;
      byte ^= ((tid >> 1) & 7) << 4;
      *reinterpret_cast<ushort4*>(smem + byte) = make_ushort4(pk[0], pk[1], pk[2], pk[3]);
    }
  }
  __syncthreads();

  // ---- MFMA: wave = (mhalf, nhalf); 4 M-tiles x 2 N-tiles of 16x16 ----
  const int mhalf = wv >> 1, nhalf = wv & 1;
  const int row = lane & 15, ksub = lane >> 4;

  int s0[4];
#pragma unroll
  for (int mt = 0; mt < 4; mt++) {
    const int wo = mhalf * 64 + mt * 16 + row;
    int ss = 2 * wo;
    if (mhalf == 1 && mt == 3) ss -= 32;  // dead tile clamp
    s0[mt] = ss;
  }
  const ushort* wq0 = wB + (size_t)(nhalf * 32 + row) * (7 * KPAD) + ksub * 8;
  const ushort* wq1 = wq0 + (size_t)16 * (7 * KPAD);

  f32x4 acc[4][2] = {};

#pragma unroll
  for (int kw = 0; kw < 7; kw++) {
#pragma unroll
    for (int kit = 0; kit < NKIT; kit++) {
      const bf16x8 b0 = *reinterpret_cast<const bf16x8*>(wq0 + kw * KPAD + kit * 32);
      const bf16x8 b1 = *reinterpret_cast<const bf16x8*>(wq1 + kw * KPAD + kit * 32);
#pragma unroll
      for (int mt = 0; mt < 4; mt++) {
        const int s = s0[mt] + kw;
        const int byte = (s * ROWB + (kit * 4 + ksub) * 16) ^ (((s >> 1) & 7) << 4);
        const bf16x8 a = *reinterpret_cast<const bf16x8*>(smem + byte);
        acc[mt][0] = __builtin_amdgcn_mfma_f32_16x16x32_bf16(a, b0, acc[mt][0], 0, 0, 0);
        acc[mt][1] = __builtin_amdgcn_mfma_f32_16x16x32_bf16(a, b1, acc[mt][1], 0, 0, 0);
      }
    }
  }

  // ---- epilogue: transpose via LDS, coalesced store ----
  __syncthreads();
  float* eLDS = reinterpret_cast<float*>(smem);  // [64][116]
#pragma unroll
  for (int mt = 0; mt < 4; mt++) {
    const int wo_b = mhalf * 64 + mt * 16 + ksub * 4;
    if (wo_b < 112) {
#pragma unroll
      for (int n = 0; n < 2; n++) {
        const int oc = nhalf * 32 + n * 16 + row;
        f32x4 r4;
#pragma unroll
        for (int r = 0; r < 4; r++) r4[r] = fmaxf(acc[mt][n][r], 0.f);
        *reinterpret_cast<f32x4*>(eLDS + oc * 116 + wo_b) = r4;
      }
    }
  }
  __syncthreads();
  for (int i = 0; i < 28; i++) {
    const int idx = i * 256 + tid;
    const int oc = idx / 112;
    const int wo = idx - oc * 112;
    out[((size_t)(b * 64 + oc) * DOUT + dd) * (HO * HO) + ho * HO + wo] =
        eLDS[oc * 116 + wo];
  }
}

// ---------------- fused maxpool 3x3 s2 SAME + gather into GEMM X layout (bf16) ----------------
__global__ void maxpool_gather(const float* __restrict__ in, ushort* __restrict__ X, int fbase) {
  const int idx = blockIdx.x * 256 + threadIdx.x;
  if (idx >= 2 * 64 * 8 * PO * PO) return;
  const int wo = idx % PO;
  const int ho = (idx / PO) % PO;
  const int rest = idx / (PO * PO);          // (b*64+c)*8+t
  const float* p = in + (size_t)rest * (HO * HO);
  float m = -1e30f;
  for (int dh = 0; dh < 3; dh++) {
    const int ih = 2 * ho + dh;
    if (ih >= HO) break;
    for (int dw = 0; dw < 3; dw++) {
      const int iw = 2 * wo + dw;
      if (iw >= HO) break;
      m = fmaxf(m, p[ih * HO + iw]);
    }
  }
  const int t = rest % 8;
  const int c = (rest / 8) % 64;
  const int b = rest / 512;
  const int r = ((b * 8 + t) * 4 + ho / 14) * 4 + (wo / 14);
  const int f = fbase + c * 196 + (ho % 14) * 14 + (wo % 14);
  X[(size_t)r * 25088 + f] = f2bf(m);
}

// ---------------- FCL1: X[256][25088] bf16 @ W1[25088][1024] f32(cvt in-kernel) ----------------
// grid (bn=8, kc=28); BM=256 BN=128 BK=64; 512 thr = 8 waves (4M x 2N), wave out 64x64 via 32x32x16
__global__ __launch_bounds__(512) void fcl1_mfma(
    const ushort* __restrict__ X, const float* __restrict__ W1, float* __restrict__ part)
{
  const int bn = blockIdx.x;
  const int kc = blockIdx.y;
  const int tid = threadIdx.x;
  const int lane = tid & 63;
  const int wv = tid >> 6;
  const int wm = wv >> 1, wn = wv & 1;
  const int l31 = lane & 31, kh = lane >> 5;

  __shared__ char xs[256 * 128];   // [r][64k] bf16, swz ((r&7)<<4)
  __shared__ char wsm[128 * 128];  // [n][64k] bf16, swz ((n&7)<<4)

  f32x16 acc[2][2] = {};

  const int kchunk0 = kc * 896;

  for (int kt = 0; kt < 14; kt++) {
    const int k0 = kchunk0 + kt * 64;
    __syncthreads();
    // stage X: 4 x 16B per thread (256 rows x 8 chunks = 2048)
#pragma unroll
    for (int i = 0; i < 4; i++) {
      const int chunk = tid + 512 * i;
      const int r = chunk >> 3, c8 = chunk & 7;
      const int4 v = *reinterpret_cast<const int4*>(X + (size_t)r * 25088 + k0 + c8 * 8);
      int byte = r * 128 + c8 * 16;
      byte ^= ((r & 7) << 4);
      *reinterpret_cast<int4*>(xs + byte) = v;
    }
    // stage W: transpose + f32->bf16; thread = (kp, nq)
    {
      const int nq = tid & 31, kp0 = tid >> 5;
#pragma unroll
      for (int h = 0; h < 2; h++) {
        const int kk = (kp0 + h * 16) * 2;
        const float4 a  = *reinterpret_cast<const float4*>(W1 + (size_t)(k0 + kk) * 1024 + bn * 128 + nq * 4);
        const float4 bq = *reinterpret_cast<const float4*>(W1 + (size_t)(k0 + kk + 1) * 1024 + bn * 128 + nq * 4);
        const float av[4] = {a.x, a.y, a.z, a.w};
        const float bv[4] = {bq.x, bq.y, bq.z, bq.w};
#pragma unroll
        for (int j = 0; j < 4; j++) {
          const int n = nq * 4 + j;
          const uint pack = (uint)f2bf(av[j]) | ((uint)f2bf(bv[j]) << 16);
          int byte = n * 128 + kk * 2;
          byte ^= ((n & 7) << 4);
          *reinterpret_cast<uint*>(wsm + byte) = pack;
        }
      }
    }
    __syncthreads();
    // compute 4 k16-steps
#pragma unroll
    for (int ks = 0; ks < 4; ks++) {
      bf16x8 af[2], bfr[2];
#pragma unroll
      for (int m = 0; m < 2; m++) {
        const int r = wm * 64 + m * 32 + l31;
        const int byte = (r * 128 + ks * 32 + kh * 16) ^ ((r & 7) << 4);
        af[m] = *reinterpret_cast<const bf16x8*>(xs + byte);
      }
#pragma unroll
      for (int n = 0; n < 2; n++) {
        const int c = wn * 64 + n * 32 + l31;
        const int byte = (c * 128 + ks * 32 + kh * 16) ^ ((c & 7) << 4);
        bfr[n] = *reinterpret_cast<const bf16x8*>(wsm + byte);
      }
#pragma unroll
      for (int m = 0; m < 2; m++)
#pragma unroll
        for (int n = 0; n < 2; n++)
          acc[m][n] = __builtin_amdgcn_mfma_f32_32x32x16_bf16(af[m], bfr[n], acc[m][n], 0, 0, 0);
    }
  }

  float* pout = part + (size_t)kc * (256 * 1024);
#pragma unroll
  for (int m = 0; m < 2; m++)
#pragma unroll
    for (int n = 0; n < 2; n++)
#pragma unroll
      for (int rg = 0; rg < 16; rg++) {
        const int row = wm * 64 + m * 32 + (rg & 3) + 8 * (rg >> 2) + 4 * kh;
        const int col = bn * 128 + wn * 64 + n * 32 + l31;
        pout[(size_t)row * 1024 + col] = acc[m][n][rg];
      }
}

__global__ void h1_reduce(const float* __restrict__ part, const float* __restrict__ b1,
                          float* __restrict__ h1) {
  const int v = blockIdx.x * 256 + threadIdx.x;  // < 65536
  if (v >= 65536) return;
  const int n4 = v & 255;
  float4 s = *reinterpret_cast<const float4*>(b1 + n4 * 4);
  for (int kc = 0; kc < 28; kc++) {
    const float4 p = *reinterpret_cast<const float4*>(part + (size_t)kc * 262144 + v * 4);
    s.x += p.x; s.y += p.y; s.z += p.z; s.w += p.w;
  }
  const float4 r = make_float4(fmaxf(s.x, 0.f), fmaxf(s.y, 0.f), fmaxf(s.z, 0.f), fmaxf(s.w, 0.f));
  *reinterpret_cast<float4*>(h1 + v * 4) = r;
}

__global__ __launch_bounds__(256) void fcl2_k(const float* __restrict__ h1,
                                              const float* __restrict__ W2,
                                              const float* __restrict__ b2,
                                              float* __restrict__ h2) {
  const int r = blockIdx.x;
  const int n = threadIdx.x;
  __shared__ float xr[1024];
  for (int i = threadIdx.x; i < 1024; i += 256) xr[i] = h1[r * 1024 + i];
  __syncthreads();
  float s = b2[n];
  for (int k = 0; k < 1024; k++) s += xr[k] * W2[k * 256 + n];
  h2[r * 256 + n] = fmaxf(s, 0.f);
}

__global__ void fcl3_k(const float* __restrict__ h2, const float* __restrict__ W3,
                       const float* __restrict__ b3, float* __restrict__ ms) {
  __shared__ float w[256];
  w[threadIdx.x] = W3[threadIdx.x];
  __syncthreads();
  const int r = threadIdx.x;
  float s = b3[0];
  for (int k = 0; k < 256; k++) s += h2[r * 256 + k] * w[k];
  ms[r] = 1.f / (1.f + expf(-s));
}

__global__ void upsample_k(const float* __restrict__ ms, float* __restrict__ mask) {
  const int idx = blockIdx.x * 256 + threadIdx.x;
  if (idx >= 2 * 16 * IHW * IHW) return;
  const int w = idx % IHW;
  const int h = (idx / IHW) % IHW;
  const int t = (idx / (IHW * IHW)) % 16;
  const int b = idx / (16 * IHW * IHW);

  const float tf = t * 0.5f - 0.25f;
  const float hf = (h + 0.5f) * (1.f / 56.f) - 0.5f;
  const float wf = (w + 0.5f) * (1.f / 56.f) - 0.5f;

  int t0 = (int)floorf(tf); const float ft = tf - t0;
  int h0 = (int)floorf(hf); const float fh = hf - h0;
  int w0 = (int)floorf(wf); const float fw = wf - w0;
  const int t1 = min(t0 + 1, 7); t0 = max(t0, 0);
  const int h1 = min(h0 + 1, 3); h0 = max(h0, 0);
  const int w1 = min(w0 + 1, 3); w0 = max(w0, 0);

  const float* p = ms + b * 128;
  auto at = [&](int tt, int hh, int ww) { return p[(tt * 4 + hh) * 4 + ww]; };
  const float c00 = at(t0, h0, w0) * (1.f - fw) + at(t0, h0, w1) * fw;
  const float c01 = at(t0, h1, w0) * (1.f - fw) + at(t0, h1, w1) * fw;
  const float c10 = at(t1, h0, w0) * (1.f - fw) + at(t1, h0, w1) * fw;
  const float c11 = at(t1, h1, w0) * (1.f - fw) + at(t1, h1, w1) * fw;
  const float c0 = c00 * (1.f - fh) + c01 * fh;
  const float c1 = c10 * (1.f - fh) + c11 * fh;
  mask[idx] = c0 * (1.f - ft) + c1 * ft;
}

// masked = rgbs*m + bg*(1-m), float4; flip -> m := 1-m
__global__ void masking_k(const float* __restrict__ rgbs, const float* __restrict__ mask,
                          const float* __restrict__ bg, float* __restrict__ out, int flip) {
  const int v = blockIdx.x * 256 + threadIdx.x;
  if (v >= 1204224) return;                 // 2*3*16*224*224/4
  const int hw4 = v % 12544;
  const int rest = v / 12544;
  const int t = rest & 15;
  const int bc = rest >> 4;
  const int c = bc % 3;
  const int b = bc / 3;
  const float4 rg = reinterpret_cast<const float4*>(rgbs)[v];
  float4 mk = reinterpret_cast<const float4*>(mask)[(b * 16 + t) * 12544 + hw4];
  if (flip) { mk.x = 1.f - mk.x; mk.y = 1.f - mk.y; mk.z = 1.f - mk.z; mk.w = 1.f - mk.w; }
  const float4 bgv = reinterpret_cast<const float4*>(bg)[c * 12544 + hw4];
  float4 o;
  o.x = rg.x * mk.x + bgv.x * (1.f - mk.x);
  o.y = rg.y * mk.y + bgv.y * (1.f - mk.y);
  o.z = rg.z * mk.z + bgv.z * (1.f - mk.z);
  o.w = rg.w * mk.w + bgv.w * (1.f - mk.w);
  reinterpret_cast<float4*>(out)[v] = o;
}

__global__ __launch_bounds__(256) void pool_sum_k(const float* __restrict__ in,
                                                  float* __restrict__ psums) {
  const int blk = blockIdx.x;
  const float* p = in + (size_t)blk * (HO * HO);
  float s = 0.f;
  for (int idx = threadIdx.x; idx < PO * PO; idx += 256) {
    const int ho = idx / PO, wo = idx % PO;
    float m = -1e30f;
    for (int dh = 0; dh < 3; dh++) {
      const int ih = 2 * ho + dh;
      if (ih >= HO) break;
      for (int dw = 0; dw < 3; dw++) {
        const int iw = 2 * wo + dw;
        if (iw >= HO) break;
        m = fmaxf(m, p[ih * HO + iw]);
      }
    }
    s += m;
  }
  __shared__ float red[256];
  red[threadIdx.x] = s;
  __syncthreads();
  for (int off = 128; off > 0; off >>= 1) {
    if (threadIdx.x < off) red[threadIdx.x] += red[threadIdx.x + off];
    __syncthreads();
  }
  if (threadIdx.x == 0) psums[blk] = red[0];
}

__global__ void logits_k(const float* __restrict__ psums, const float* __restrict__ Wl,
                         const float* __restrict__ bl, float* __restrict__ out) {
  const int idx = blockIdx.x * 256 + threadIdx.x;
  if (idx >= 800) return;
  const int b = idx / 400, l = idx % 400;
  float s = bl[l];
  for (int oc = 0; oc < 64; oc++) {
    float ps = 0.f;
    for (int t = 0; t < 8; t++) ps += psums[(b * 64 + oc) * 8 + t];
    s += (ps * (1.f / 25088.f)) * Wl[oc * 400 + l];
  }
  out[b * 400 + l] = s;
}

extern "C" void kernel_launch(void* const* d_in, const int* in_sizes, int n_in,
                              void* d_out, int out_size, void* d_ws, size_t ws_size,
                              hipStream_t stream) {
  const float* rgbs   = (const float*)d_in[0];
  const float* flows  = (const float*)d_in[1];
  const float* bg     = (const float*)d_in[2];
  const float* w_rgb  = (const float*)d_in[3];
  const float* w_flow = (const float*)d_in[4];
  const float* w_feat = (const float*)d_in[5];
  const float* W1     = (const float*)d_in[6];
  const float* b1     = (const float*)d_in[7];
  const float* W2     = (const float*)d_in[8];
  const float* b2     = (const float*)d_in[9];
  const float* W3     = (const float*)d_in[10];
  const float* b3     = (const float*)d_in[11];
  const float* Wl     = (const float*)d_in[12];
  const float* bl     = (const float*)d_in[13];
  float* out = (float*)d_out;

  float* ws = (float*)d_ws;
  float* convbuf = ws;                            // 12,845,056 f
  float* part    = ws;                            // 7,340,032 f (aliases convbuf; disjoint in time)
  ushort* X      = (ushort*)(ws + 12845056);      // 6,422,528 ush (3,211,264 f)
  float* masked  = ws + 12845056;                 // 4,816,896 f (aliases X; after fcl1)
  float* h1      = ws + 19267584;                 // 262,144
  float* h2      = ws + 19529728;                 // 65,536
  float* msmall  = ws + 19595264;                 // 256
  float* psums0  = ws + 19595520;                 // 1024
  float* psums1  = ws + 19596544;                 // 1024
  ushort* wrgb_b  = (ushort*)(ws + 19600000);     // 71,680 ush
  ushort* wflow_b = wrgb_b + 71680;               // 57,344 ush
  ushort* wfeat_b = wflow_b + 57344;              // 71,680 ush

  float* mask_full = out + 1600;

  const dim3 cgrid(112, 8, 2);

  wprep<3><<<(64 * 7 * 160 + 255) / 256, 256, 0, stream>>>(w_rgb, wrgb_b);
  wprep<2><<<(64 * 7 * 128 + 255) / 256, 256, 0, stream>>>(w_flow, wflow_b);
  wprep<3><<<(64 * 7 * 160 + 255) / 256, 256, 0, stream>>>(w_feat, wfeat_b);

  conv_mfma<3><<<cgrid, 256, 0, stream>>>(rgbs, wrgb_b, convbuf);
  maxpool_gather<<<(3211264 + 255) / 256, 256, 0, stream>>>(convbuf, X, 0);
  conv_mfma<2><<<cgrid, 256, 0, stream>>>(flows, wflow_b, convbuf);
  maxpool_gather<<<(3211264 + 255) / 256, 256, 0, stream>>>(convbuf, X, 12544);

  fcl1_mfma<<<dim3(8, 28), 512, 0, stream>>>(X, W1, part);
  h1_reduce<<<256, 256, 0, stream>>>(part, b1, h1);
  fcl2_k<<<256, 256, 0, stream>>>(h1, W2, b2, h2);
  fcl3_k<<<1, 256, 0, stream>>>(h2, W3, b3, msmall);
  upsample_k<<<(1605632 + 255) / 256, 256, 0, stream>>>(msmall, mask_full);

  masking_k<<<(1204224 + 255) / 256, 256, 0, stream>>>(rgbs, mask_full, bg, masked, 0);
  conv_mfma<3><<<cgrid, 256, 0, stream>>>(masked, wfeat_b, convbuf);
  pool_sum_k<<<1024, 256, 0, stream>>>(convbuf, psums0);

  masking_k<<<(1204224 + 255) / 256, 256, 0, stream>>>(rgbs, mask_full, bg, masked, 1);
  conv_mfma<3><<<cgrid, 256, 0, stream>>>(masked, wfeat_b, convbuf);
  pool_sum_k<<<1024, 256, 0, stream>>>(convbuf, psums1);

  logits_k<<<4, 256, 0, stream>>>(psums0, Wl, bl, out);
  logits_k<<<4, 256, 0, stream>>>(psums1, Wl, bl, out + 800);
}